// Round 8
// baseline (769.211 us; speedup 1.0000x reference)
//
#include <hip/hip_runtime.h>
#include <cstdint>

// InstantNGP hash-grid encoder, MI355X, v6.
// D=3, L=16, F=2, N_MIN=16, PLS=2. Levels 0..2 dense, 3..15 hashed (2^19).
// Measured model: random-gather service wall ~0.25 unique 64B-line req/cyc/CU
// (v1/v3/v4 all converge there); hashed levels need 6 line-req/pt (pair-merge
// + odd-i0 fixup) -> 78M requests, irreducible. v5 lesson: wave-shuffle
// transpose (170 us) == non-contiguous transpose (172 us) -> lane mapping was
// NOT the bottleneck; v3's final_kernel (dense + 13 coalesced ws-row reads +
// LDS transpose + plain cached loads/stores) measured 80 us doing MORE work.
// v6: mega = hashed levels only (13 zones, ~470 us predicted); final = v3
// recipe with halved LDS (two 4-quad passes, 16.4 KB -> 8 blocks/CU).

static constexpr uint32_t kOff[17] = {
    0u, 4913u, 40850u, 315475u, 839763u, 1364051u, 1888339u, 2412627u,
    2936915u, 3461203u, 3985491u, 4509779u, 5034067u, 5558355u, 6082643u,
    6606931u, 7131219u};
// kOff[l] for l>=3 is 315475 + (l-3)*524288 (each hashed table 2^19 entries).

static constexpr uint32_t P1 = 2654435761u;
static constexpr uint32_t P2 = 805459861u;

// 16B vector with 8B alignment (table pair-loads never straddle a 64B line).
typedef float f4a8 __attribute__((ext_vector_type(4), aligned(8)));
typedef float v2f __attribute__((ext_vector_type(2)));
typedef float v4f __attribute__((ext_vector_type(4)));

__device__ __forceinline__ float2 ntload2(const float2* p) {
  v2f t = __builtin_nontemporal_load((const v2f*)p);
  return make_float2(t[0], t[1]);
}
__device__ __forceinline__ void ntstore2(float2* p, float a, float b) {
  v2f t;
  t[0] = a;
  t[1] = b;
  __builtin_nontemporal_store(t, (v2f*)p);
}
__device__ __forceinline__ void ntstore4(float4* p, float a, float b, float c,
                                         float d) {
  v4f t;
  t[0] = a;
  t[1] = b;
  t[2] = c;
  t[3] = d;
  __builtin_nontemporal_store(t, (v4f*)p);
}

__device__ __forceinline__ float to_unit(float v) {
  // x = (in + 1) / 2 ; *0.5 exact, matches reference
  return __fmul_rn(__fadd_rn(v, 1.0f), 0.5f);
}

// pos = x*scale + 0.5 with separate mul/add rounding (match reference).
__device__ __forceinline__ void pos_decomp_rt(float x0, float x1, float x2,
                                              float scale, uint32_t& i0,
                                              uint32_t& i1, uint32_t& i2,
                                              float& f0, float& f1, float& f2) {
  float p0 = __fadd_rn(__fmul_rn(x0, scale), 0.5f);
  float p1 = __fadd_rn(__fmul_rn(x1, scale), 0.5f);
  float p2 = __fadd_rn(__fmul_rn(x2, scale), 0.5f);
  float g0 = floorf(p0), g1 = floorf(p1), g2 = floorf(p2);
  f0 = __fsub_rn(p0, g0);
  f1 = __fsub_rn(p1, g1);
  f2 = __fsub_rn(p2, g2);
  i0 = (uint32_t)g0;
  i1 = (uint32_t)g1;
  i2 = (uint32_t)g2;
}

// Hashed level, runtime scale/table-base (identical for all levels >= 3:
// mask 2^19-1, primes fixed). Reference corner order and fp op order kept.
__device__ __forceinline__ void hashed_accum_rt(float x0, float x1, float x2,
                                                float scale,
                                                const float2* __restrict__ t2,
                                                float& A0, float& A1) {
  constexpr uint32_t mask = 0x7FFFFu;  // hmap = 2^19
  uint32_t i0, i1, i2;
  float f0, f1, f2;
  pos_decomp_rt(x0, x1, x2, scale, i0, i1, i2, f0, f1, f2);

  const float w0l = __fsub_rn(1.0f, f0), w0h = f0;
  const float w1v[2] = {__fsub_rn(1.0f, f1), f1};
  const float w2v[2] = {__fsub_rn(1.0f, f2), f2};
  uint32_t h1v[2], h2v[2];
  h1v[0] = i1 * P1;
  h1v[1] = h1v[0] + P1;
  h2v[0] = i2 * P2;
  h2v[1] = h2v[0] + P2;

  const bool odd = (i0 & 1u) != 0u;
  float acc0 = A0, acc1 = A1;
#pragma unroll
  for (int b2 = 0; b2 < 2; ++b2) {
#pragma unroll
    for (int b1 = 0; b1 < 2; ++b1) {
      const uint32_t ex = h1v[b1] ^ h2v[b2];
      const uint32_t ilo = (i0 ^ ex) & mask;
      // one 16B load covers entries {ilo&~1, ilo|1}
      const f4a8 v = *(const f4a8*)(t2 + (ilo & ~1u));
      const bool hs = (ilo & 1u) != 0u;
      float eL0 = hs ? v.z : v.x;
      float eL1 = hs ? v.w : v.y;
      float eH0 = hs ? v.x : v.z;  // valid when i0 even (ihi == ilo^1)
      float eH1 = hs ? v.y : v.w;
      if (odd) {
        const uint32_t ihi = ((i0 + 1u) ^ ex) & mask;
        const float2 e = t2[ihi];
        eH0 = e.x;
        eH1 = e.y;
      }
      const float wl = __fmul_rn(__fmul_rn(w0l, w1v[b1]), w2v[b2]);
      const float wh = __fmul_rn(__fmul_rn(w0h, w1v[b1]), w2v[b2]);
      acc0 = __fadd_rn(acc0, __fmul_rn(wl, eL0));
      acc1 = __fadd_rn(acc1, __fmul_rn(wl, eL1));
      acc0 = __fadd_rn(acc0, __fmul_rn(wh, eH0));
      acc1 = __fadd_rn(acc1, __fmul_rn(wh, eH1));
    }
  }
  A0 = acc0;
  A1 = acc1;
}

// Dense level (LV < 3): corner pair always adjacent -> one 16B load.
template <int LV>
__device__ __forceinline__ void dense_accum(float x0, float x1, float x2,
                                            const float* __restrict__ embf,
                                            float& A0, float& A1) {
  static_assert(LV < 3, "");
  constexpr uint32_t res = 16u << LV;
  constexpr uint32_t off = kOff[LV];
  constexpr uint32_t s1 = res + 1u, s2 = s1 * s1;
  constexpr float scale = (float)res - 1.0f;
  uint32_t i0, i1, i2;
  float f0, f1, f2;
  pos_decomp_rt(x0, x1, x2, scale, i0, i1, i2, f0, f1, f2);

  const float w0l = __fsub_rn(1.0f, f0), w0h = f0;
  const float w1v[2] = {__fsub_rn(1.0f, f1), f1};
  const float w2v[2] = {__fsub_rn(1.0f, f2), f2};
  const uint32_t base = i0 + i1 * s1 + i2 * s2;
  const float2* t2 = (const float2*)embf + off;

  float acc0 = A0, acc1 = A1;
#pragma unroll
  for (int b2 = 0; b2 < 2; ++b2) {
#pragma unroll
    for (int b1 = 0; b1 < 2; ++b1) {
      const uint32_t idx = base + (b1 ? s1 : 0u) + (b2 ? s2 : 0u);
      const f4a8 v = *(const f4a8*)(t2 + idx);  // {e[idx], e[idx+1]}
      const float wl = __fmul_rn(__fmul_rn(w0l, w1v[b1]), w2v[b2]);
      const float wh = __fmul_rn(__fmul_rn(w0h, w1v[b1]), w2v[b2]);
      acc0 = __fadd_rn(acc0, __fmul_rn(wl, v.x));
      acc1 = __fadd_rn(acc1, __fmul_rn(wl, v.y));
      acc0 = __fadd_rn(acc0, __fmul_rn(wh, v.z));
      acc1 = __fadd_rn(acc1, __fmul_rn(wh, v.w));
    }
  }
  A0 = acc0;
  A1 = acc1;
}

// --------------------------- mega gather kernel ---------------------------
// zone z in 0..12 -> hashed level z+3. 2 points/thread; ws layout [16][B]
// float2 (rows 3..15 written here; rows 0..2 unused).

__global__ __launch_bounds__(256) void mega_kernel(
    const float* __restrict__ in, const float* __restrict__ embf,
    float2* __restrict__ ws, int B, int NB) {
  const int zone = blockIdx.x / NB;
  const int q = (blockIdx.x - zone * NB) * 256 + threadIdx.x;
  const int p0 = q << 1;
  if (p0 >= B) return;
  const bool hasB = (p0 + 1) < B;

  float xA0, xA1, xA2, xB0 = 0.f, xB1 = 0.f, xB2 = 0.f;
  if (hasB) {
    const float2* in2 = (const float2*)in;
    const size_t b3 = (size_t)q * 3;
    const float2 u0 = ntload2(in2 + b3);
    const float2 u1 = ntload2(in2 + b3 + 1);
    const float2 u2 = ntload2(in2 + b3 + 2);
    xA0 = to_unit(u0.x);
    xA1 = to_unit(u0.y);
    xA2 = to_unit(u1.x);
    xB0 = to_unit(u1.y);
    xB1 = to_unit(u2.x);
    xB2 = to_unit(u2.y);
  } else {  // last point when B odd: avoid reading past in[]
    xA0 = to_unit(in[(size_t)p0 * 3 + 0]);
    xA1 = to_unit(in[(size_t)p0 * 3 + 1]);
    xA2 = to_unit(in[(size_t)p0 * 3 + 2]);
  }
  const bool pair4 = hasB && ((B & 1) == 0);  // 16B-aligned float4 ws store

  const int level = zone + 3;  // 3..15
  const float scale = (float)(int)((16u << level) - 1u);
  const float2* t2 =
      (const float2*)embf + (315475u + (uint32_t)(level - 3) * 524288u);
  float2* wsl = ws + (size_t)level * B;

  float a0 = 0.0f, a1 = 0.0f;
  hashed_accum_rt(xA0, xA1, xA2, scale, t2, a0, a1);
  if (pair4) {
    float b0 = 0.0f, b1 = 0.0f;
    hashed_accum_rt(xB0, xB1, xB2, scale, t2, b0, b1);
    ntstore4((float4*)(wsl + p0), a0, a1, b0, b1);
  } else {
    ntstore2(wsl + p0, a0, a1);
    if (hasB) {
      float b0 = 0.0f, b1 = 0.0f;
      hashed_accum_rt(xB0, xB1, xB2, scale, t2, b0, b1);
      ntstore2(wsl + p0 + 1, b0, b1);
    }
  }
}

// ---------------- final kernel: dense + ws gather + LDS transpose ----------
// v3 recipe (measured 80 us) with LDS halved: two 4-quad passes, 16448 B ->
// 8 blocks/CU. Plain cached loads/stores (NT hints hurt the v4/v5 transpose).
// Writes: each 4-lane group covers one full 64B line of out.

__global__ __launch_bounds__(256) void final_kernel(
    const float* __restrict__ in, const float* __restrict__ embf,
    const float2* __restrict__ ws, float4* __restrict__ out4, int B) {
  __shared__ float4 lds[4 * 257];
  const int tid = (int)threadIdx.x;
  const int p = blockIdx.x * 256 + tid;

  float a[32];
#pragma unroll
  for (int i = 0; i < 32; ++i) a[i] = 0.0f;

  if (p < B) {
    const float x0 = to_unit(in[(size_t)p * 3 + 0]);
    const float x1 = to_unit(in[(size_t)p * 3 + 1]);
    const float x2 = to_unit(in[(size_t)p * 3 + 2]);
    dense_accum<0>(x0, x1, x2, embf, a[0], a[1]);
    dense_accum<1>(x0, x1, x2, embf, a[2], a[3]);
    dense_accum<2>(x0, x1, x2, embf, a[4], a[5]);
#pragma unroll
    for (int l = 3; l < 16; ++l) {  // row-coalesced: 64 lanes x 8B contiguous
      const float2 e = ws[(size_t)l * B + p];
      a[2 * l] = e.x;
      a[2 * l + 1] = e.y;
    }
  }

  const size_t gbase = (size_t)blockIdx.x * 2048;
  const size_t lim = (size_t)B * 8;
#pragma unroll
  for (int half = 0; half < 2; ++half) {
    if (half) __syncthreads();  // previous pass's reads done before overwrite
#pragma unroll
    for (int w = 0; w < 4; ++w) {
      const int qd = half * 4 + w;
      lds[w * 257 + tid] =
          make_float4(a[4 * qd], a[4 * qd + 1], a[4 * qd + 2], a[4 * qd + 3]);
    }
    __syncthreads();
#pragma unroll
    for (int k = 0; k < 4; ++k) {
      const int gl = k * 256 + tid;  // 0..1023
      const int pt = gl >> 2;        // point within block 0..255
      const int qw = gl & 3;         // quad within half 0..3
      const size_t g = gbase + (size_t)pt * 8 + (size_t)(half * 4 + qw);
      if (g < lim) out4[g] = lds[qw * 257 + pt];
    }
  }
}

// ---------------- fallback (ws too small): 8 levels/kernel ----------------

template <int LV>
__device__ __forceinline__ void any_accum(float x0, float x1, float x2,
                                          const float* __restrict__ embf,
                                          float& A0, float& A1) {
  if constexpr (LV < 3) {
    dense_accum<LV>(x0, x1, x2, embf, A0, A1);
  } else {
    constexpr float scale = (float)(16u << LV) - 1.0f;
    const float2* t2 = (const float2*)embf + kOff[LV];
    hashed_accum_rt(x0, x1, x2, scale, t2, A0, A1);
  }
}

template <int LBASE>
__global__ __launch_bounds__(256) void grid_enc_kernel(
    const float* __restrict__ in, const float* __restrict__ embf,
    float* __restrict__ out, int B) {
  const int p = blockIdx.x * 256 + threadIdx.x;
  if (p >= B) return;
  const float x0 = to_unit(in[(size_t)p * 3 + 0]);
  const float x1 = to_unit(in[(size_t)p * 3 + 1]);
  const float x2 = to_unit(in[(size_t)p * 3 + 2]);

  float a[16];
#pragma unroll
  for (int i = 0; i < 16; ++i) a[i] = 0.0f;

  any_accum<LBASE + 0>(x0, x1, x2, embf, a[0], a[1]);
  any_accum<LBASE + 1>(x0, x1, x2, embf, a[2], a[3]);
  any_accum<LBASE + 2>(x0, x1, x2, embf, a[4], a[5]);
  any_accum<LBASE + 3>(x0, x1, x2, embf, a[6], a[7]);
  any_accum<LBASE + 4>(x0, x1, x2, embf, a[8], a[9]);
  any_accum<LBASE + 5>(x0, x1, x2, embf, a[10], a[11]);
  any_accum<LBASE + 6>(x0, x1, x2, embf, a[12], a[13]);
  any_accum<LBASE + 7>(x0, x1, x2, embf, a[14], a[15]);

  float4* __restrict__ o = (float4*)(out + (size_t)p * 32 + LBASE * 2);
  o[0] = make_float4(a[0], a[1], a[2], a[3]);
  o[1] = make_float4(a[4], a[5], a[6], a[7]);
  o[2] = make_float4(a[8], a[9], a[10], a[11]);
  o[3] = make_float4(a[12], a[13], a[14], a[15]);
}

extern "C" void kernel_launch(void* const* d_in, const int* in_sizes, int n_in,
                              void* d_out, int out_size, void* d_ws,
                              size_t ws_size, hipStream_t stream) {
  const float* in = (const float*)d_in[0];
  const float* emb = (const float*)d_in[1];
  float* out = (float*)d_out;
  const int B = in_sizes[0] / 3;
  const size_t ws_needed = (size_t)16 * (size_t)B * sizeof(float2);

  if (ws_size >= ws_needed) {
    float2* ws = (float2*)d_ws;
    const int NB = ((B + 1) / 2 + 255) / 256;  // blocks per zone
    mega_kernel<<<NB * 13, 256, 0, stream>>>(in, emb, ws, B, NB);
    const int blocksP = (B + 255) / 256;
    final_kernel<<<blocksP, 256, 0, stream>>>(in, emb, ws, (float4*)out, B);
  } else {
    const int blocksP = (B + 255) / 256;
    grid_enc_kernel<0><<<blocksP, 256, 0, stream>>>(in, emb, out, B);
    grid_enc_kernel<8><<<blocksP, 256, 0, stream>>>(in, emb, out, B);
  }
}

// Round 10
// 755.975 us; speedup vs baseline: 1.0175x; 1.0175x over previous
//
#include <hip/hip_runtime.h>
#include <cstdint>

// InstantNGP hash-grid encoder, MI355X, v7 (resubmit; R9 was an infra fail).
// D=3, L=16, F=2, N_MIN=16, PLS=2. Levels 0..2 dense, 3..15 hashed (2^19).
// Measured model: hashed gathers are bound by random 64B-line request service
// (~160 G req/s chip-wide); 6 req/pt x 13 levels = 78M -> ~490 us mega floor
// (v4/v6 both measured 490-536 matching). v6 lesson: final kernel MUST store
// wave-contiguous whole lines in one instruction; splitting each 128B output
// row into two temporally-separated 64B half-stores (LDS-halving) cost
// 80 -> 279 us (v2's partial-line failure mode again).
// v7: final reverted to exact v3 structure (8x257 float4 LDS, contiguous
// 1KB/wave stores, measured 80 us); mega goes 4 points/thread for deeper MLP
// at the request wall.

static constexpr uint32_t kOff[17] = {
    0u, 4913u, 40850u, 315475u, 839763u, 1364051u, 1888339u, 2412627u,
    2936915u, 3461203u, 3985491u, 4509779u, 5034067u, 5558355u, 6082643u,
    6606931u, 7131219u};
// kOff[l] for l>=3 is 315475 + (l-3)*524288 (each hashed table 2^19 entries).

static constexpr uint32_t P1 = 2654435761u;
static constexpr uint32_t P2 = 805459861u;

// 16B vector with 8B alignment (table pair-loads never straddle a 128B line).
typedef float f4a8 __attribute__((ext_vector_type(4), aligned(8)));
typedef float v2f __attribute__((ext_vector_type(2)));
typedef float v4f __attribute__((ext_vector_type(4)));

__device__ __forceinline__ float2 ntload2(const float2* p) {
  v2f t = __builtin_nontemporal_load((const v2f*)p);
  return make_float2(t[0], t[1]);
}
__device__ __forceinline__ float4 ntload4(const float4* p) {
  v4f t = __builtin_nontemporal_load((const v4f*)p);
  return make_float4(t[0], t[1], t[2], t[3]);
}
__device__ __forceinline__ void ntstore2(float2* p, float a, float b) {
  v2f t;
  t[0] = a;
  t[1] = b;
  __builtin_nontemporal_store(t, (v2f*)p);
}
__device__ __forceinline__ void ntstore4(float4* p, float a, float b, float c,
                                         float d) {
  v4f t;
  t[0] = a;
  t[1] = b;
  t[2] = c;
  t[3] = d;
  __builtin_nontemporal_store(t, (v4f*)p);
}

__device__ __forceinline__ float to_unit(float v) {
  // x = (in + 1) / 2 ; *0.5 exact, matches reference
  return __fmul_rn(__fadd_rn(v, 1.0f), 0.5f);
}

// pos = x*scale + 0.5 with separate mul/add rounding (match reference).
__device__ __forceinline__ void pos_decomp_rt(float x0, float x1, float x2,
                                              float scale, uint32_t& i0,
                                              uint32_t& i1, uint32_t& i2,
                                              float& f0, float& f1, float& f2) {
  float p0 = __fadd_rn(__fmul_rn(x0, scale), 0.5f);
  float p1 = __fadd_rn(__fmul_rn(x1, scale), 0.5f);
  float p2 = __fadd_rn(__fmul_rn(x2, scale), 0.5f);
  float g0 = floorf(p0), g1 = floorf(p1), g2 = floorf(p2);
  f0 = __fsub_rn(p0, g0);
  f1 = __fsub_rn(p1, g1);
  f2 = __fsub_rn(p2, g2);
  i0 = (uint32_t)g0;
  i1 = (uint32_t)g1;
  i2 = (uint32_t)g2;
}

// Hashed level, runtime scale/table-base (identical for all levels >= 3:
// mask 2^19-1, primes fixed). Reference corner order and fp op order kept.
__device__ __forceinline__ void hashed_accum_rt(float x0, float x1, float x2,
                                                float scale,
                                                const float2* __restrict__ t2,
                                                float& A0, float& A1) {
  constexpr uint32_t mask = 0x7FFFFu;  // hmap = 2^19
  uint32_t i0, i1, i2;
  float f0, f1, f2;
  pos_decomp_rt(x0, x1, x2, scale, i0, i1, i2, f0, f1, f2);

  const float w0l = __fsub_rn(1.0f, f0), w0h = f0;
  const float w1v[2] = {__fsub_rn(1.0f, f1), f1};
  const float w2v[2] = {__fsub_rn(1.0f, f2), f2};
  uint32_t h1v[2], h2v[2];
  h1v[0] = i1 * P1;
  h1v[1] = h1v[0] + P1;
  h2v[0] = i2 * P2;
  h2v[1] = h2v[0] + P2;

  const bool odd = (i0 & 1u) != 0u;
  float acc0 = A0, acc1 = A1;
#pragma unroll
  for (int b2 = 0; b2 < 2; ++b2) {
#pragma unroll
    for (int b1 = 0; b1 < 2; ++b1) {
      const uint32_t ex = h1v[b1] ^ h2v[b2];
      const uint32_t ilo = (i0 ^ ex) & mask;
      // one 16B load covers entries {ilo&~1, ilo|1}
      const f4a8 v = *(const f4a8*)(t2 + (ilo & ~1u));
      const bool hs = (ilo & 1u) != 0u;
      float eL0 = hs ? v.z : v.x;
      float eL1 = hs ? v.w : v.y;
      float eH0 = hs ? v.x : v.z;  // valid when i0 even (ihi == ilo^1)
      float eH1 = hs ? v.y : v.w;
      if (odd) {
        const uint32_t ihi = ((i0 + 1u) ^ ex) & mask;
        const float2 e = t2[ihi];
        eH0 = e.x;
        eH1 = e.y;
      }
      const float wl = __fmul_rn(__fmul_rn(w0l, w1v[b1]), w2v[b2]);
      const float wh = __fmul_rn(__fmul_rn(w0h, w1v[b1]), w2v[b2]);
      acc0 = __fadd_rn(acc0, __fmul_rn(wl, eL0));
      acc1 = __fadd_rn(acc1, __fmul_rn(wl, eL1));
      acc0 = __fadd_rn(acc0, __fmul_rn(wh, eH0));
      acc1 = __fadd_rn(acc1, __fmul_rn(wh, eH1));
    }
  }
  A0 = acc0;
  A1 = acc1;
}

// Dense level (LV < 3): corner pair always adjacent -> one 16B load.
template <int LV>
__device__ __forceinline__ void dense_accum(float x0, float x1, float x2,
                                            const float* __restrict__ embf,
                                            float& A0, float& A1) {
  static_assert(LV < 3, "");
  constexpr uint32_t res = 16u << LV;
  constexpr uint32_t off = kOff[LV];
  constexpr uint32_t s1 = res + 1u, s2 = s1 * s1;
  constexpr float scale = (float)res - 1.0f;
  uint32_t i0, i1, i2;
  float f0, f1, f2;
  pos_decomp_rt(x0, x1, x2, scale, i0, i1, i2, f0, f1, f2);

  const float w0l = __fsub_rn(1.0f, f0), w0h = f0;
  const float w1v[2] = {__fsub_rn(1.0f, f1), f1};
  const float w2v[2] = {__fsub_rn(1.0f, f2), f2};
  const uint32_t base = i0 + i1 * s1 + i2 * s2;
  const float2* t2 = (const float2*)embf + off;

  float acc0 = A0, acc1 = A1;
#pragma unroll
  for (int b2 = 0; b2 < 2; ++b2) {
#pragma unroll
    for (int b1 = 0; b1 < 2; ++b1) {
      const uint32_t idx = base + (b1 ? s1 : 0u) + (b2 ? s2 : 0u);
      const f4a8 v = *(const f4a8*)(t2 + idx);  // {e[idx], e[idx+1]}
      const float wl = __fmul_rn(__fmul_rn(w0l, w1v[b1]), w2v[b2]);
      const float wh = __fmul_rn(__fmul_rn(w0h, w1v[b1]), w2v[b2]);
      acc0 = __fadd_rn(acc0, __fmul_rn(wl, v.x));
      acc1 = __fadd_rn(acc1, __fmul_rn(wl, v.y));
      acc0 = __fadd_rn(acc0, __fmul_rn(wh, v.z));
      acc1 = __fadd_rn(acc1, __fmul_rn(wh, v.w));
    }
  }
  A0 = acc0;
  A1 = acc1;
}

// ----------------------- mega gather, 4 points/thread -----------------------
// zone z in 0..12 -> hashed level z+3. Requires B % 4 == 0.
// ws layout [16][B] float2 (rows 3..15 written here).

__global__ __launch_bounds__(256) void mega4_kernel(
    const float* __restrict__ in, const float* __restrict__ embf,
    float2* __restrict__ ws, int B, int NB) {
  const int zone = blockIdx.x / NB;
  const int q = (blockIdx.x - zone * NB) * 256 + threadIdx.x;
  const int p0 = q << 2;
  if (p0 >= B) return;

  const float4* in4 = (const float4*)in;
  const size_t b3 = (size_t)q * 3;
  const float4 u0 = ntload4(in4 + b3);
  const float4 u1 = ntload4(in4 + b3 + 1);
  const float4 u2 = ntload4(in4 + b3 + 2);

  const int level = zone + 3;  // 3..15
  const float scale = (float)(int)((16u << level) - 1u);
  const float2* t2 =
      (const float2*)embf + (315475u + (uint32_t)(level - 3) * 524288u);
  float2* wsl = ws + (size_t)level * B;

  float a0 = 0.f, a1 = 0.f, b0 = 0.f, b1 = 0.f;
  float c0 = 0.f, c1 = 0.f, d0 = 0.f, d1 = 0.f;
  hashed_accum_rt(to_unit(u0.x), to_unit(u0.y), to_unit(u0.z), scale, t2, a0,
                  a1);
  hashed_accum_rt(to_unit(u0.w), to_unit(u1.x), to_unit(u1.y), scale, t2, b0,
                  b1);
  hashed_accum_rt(to_unit(u1.z), to_unit(u1.w), to_unit(u2.x), scale, t2, c0,
                  c1);
  hashed_accum_rt(to_unit(u2.y), to_unit(u2.z), to_unit(u2.w), scale, t2, d0,
                  d1);
  ntstore4((float4*)(wsl + p0), a0, a1, b0, b1);
  ntstore4((float4*)(wsl + p0 + 2), c0, c1, d0, d1);
}

// 2-points/thread variant for B % 4 != 0 (handles odd B too).
__global__ __launch_bounds__(256) void mega2_kernel(
    const float* __restrict__ in, const float* __restrict__ embf,
    float2* __restrict__ ws, int B, int NB) {
  const int zone = blockIdx.x / NB;
  const int q = (blockIdx.x - zone * NB) * 256 + threadIdx.x;
  const int p0 = q << 1;
  if (p0 >= B) return;
  const bool hasB = (p0 + 1) < B;

  float xA0, xA1, xA2, xB0 = 0.f, xB1 = 0.f, xB2 = 0.f;
  if (hasB) {
    const float2* in2 = (const float2*)in;
    const size_t b3 = (size_t)q * 3;
    const float2 u0 = ntload2(in2 + b3);
    const float2 u1 = ntload2(in2 + b3 + 1);
    const float2 u2 = ntload2(in2 + b3 + 2);
    xA0 = to_unit(u0.x);
    xA1 = to_unit(u0.y);
    xA2 = to_unit(u1.x);
    xB0 = to_unit(u1.y);
    xB1 = to_unit(u2.x);
    xB2 = to_unit(u2.y);
  } else {
    xA0 = to_unit(in[(size_t)p0 * 3 + 0]);
    xA1 = to_unit(in[(size_t)p0 * 3 + 1]);
    xA2 = to_unit(in[(size_t)p0 * 3 + 2]);
  }
  const bool pair4 = hasB && ((B & 1) == 0);

  const int level = zone + 3;
  const float scale = (float)(int)((16u << level) - 1u);
  const float2* t2 =
      (const float2*)embf + (315475u + (uint32_t)(level - 3) * 524288u);
  float2* wsl = ws + (size_t)level * B;

  float a0 = 0.0f, a1 = 0.0f;
  hashed_accum_rt(xA0, xA1, xA2, scale, t2, a0, a1);
  if (pair4) {
    float b0 = 0.0f, b1 = 0.0f;
    hashed_accum_rt(xB0, xB1, xB2, scale, t2, b0, b1);
    ntstore4((float4*)(wsl + p0), a0, a1, b0, b1);
  } else {
    ntstore2(wsl + p0, a0, a1);
    if (hasB) {
      float b0 = 0.0f, b1 = 0.0f;
      hashed_accum_rt(xB0, xB1, xB2, scale, t2, b0, b1);
      ntstore2(wsl + p0 + 1, b0, b1);
    }
  }
}

// ---------------- final kernel: exact v3 structure (measured 80 us) --------
// dense levels + 13 row-coalesced ws reads + 8x257 float4 LDS transpose +
// wave-contiguous 1KB stores (one instruction covers 8 whole 128B lines).
// Plain cached loads/stores.

__global__ __launch_bounds__(256) void final_kernel(
    const float* __restrict__ in, const float* __restrict__ embf,
    const float2* __restrict__ ws, float4* __restrict__ out4, int B) {
  __shared__ float4 lds[8 * 257];  // stride 257 breaks worst conflicts
  const int tid = (int)threadIdx.x;
  const int p = blockIdx.x * 256 + tid;

  float a[32];
#pragma unroll
  for (int i = 0; i < 32; ++i) a[i] = 0.0f;

  if (p < B) {
    const float x0 = to_unit(in[(size_t)p * 3 + 0]);
    const float x1 = to_unit(in[(size_t)p * 3 + 1]);
    const float x2 = to_unit(in[(size_t)p * 3 + 2]);
    dense_accum<0>(x0, x1, x2, embf, a[0], a[1]);
    dense_accum<1>(x0, x1, x2, embf, a[2], a[3]);
    dense_accum<2>(x0, x1, x2, embf, a[4], a[5]);
#pragma unroll
    for (int l = 3; l < 16; ++l) {  // row-coalesced: 64 lanes x 8B contiguous
      const float2 e = ws[(size_t)l * B + p];
      a[2 * l] = e.x;
      a[2 * l + 1] = e.y;
    }
  }

#pragma unroll
  for (int w = 0; w < 8; ++w)
    lds[w * 257 + tid] =
        make_float4(a[4 * w], a[4 * w + 1], a[4 * w + 2], a[4 * w + 3]);
  __syncthreads();

  const size_t gbase = (size_t)blockIdx.x * 2048;
  const size_t lim = (size_t)B * 8;
#pragma unroll
  for (int j = 0; j < 8; ++j) {
    const int gl = j * 256 + tid;
    const size_t g = gbase + gl;
    if (g < lim) out4[g] = lds[(gl & 7) * 257 + (gl >> 3)];
  }
}

// ---------------- fallback (ws too small): 8 levels/kernel ----------------

template <int LV>
__device__ __forceinline__ void any_accum(float x0, float x1, float x2,
                                          const float* __restrict__ embf,
                                          float& A0, float& A1) {
  if constexpr (LV < 3) {
    dense_accum<LV>(x0, x1, x2, embf, A0, A1);
  } else {
    constexpr float scale = (float)(16u << LV) - 1.0f;
    const float2* t2 = (const float2*)embf + kOff[LV];
    hashed_accum_rt(x0, x1, x2, scale, t2, A0, A1);
  }
}

template <int LBASE>
__global__ __launch_bounds__(256) void grid_enc_kernel(
    const float* __restrict__ in, const float* __restrict__ embf,
    float* __restrict__ out, int B) {
  const int p = blockIdx.x * 256 + threadIdx.x;
  if (p >= B) return;
  const float x0 = to_unit(in[(size_t)p * 3 + 0]);
  const float x1 = to_unit(in[(size_t)p * 3 + 1]);
  const float x2 = to_unit(in[(size_t)p * 3 + 2]);

  float a[16];
#pragma unroll
  for (int i = 0; i < 16; ++i) a[i] = 0.0f;

  any_accum<LBASE + 0>(x0, x1, x2, embf, a[0], a[1]);
  any_accum<LBASE + 1>(x0, x1, x2, embf, a[2], a[3]);
  any_accum<LBASE + 2>(x0, x1, x2, embf, a[4], a[5]);
  any_accum<LBASE + 3>(x0, x1, x2, embf, a[6], a[7]);
  any_accum<LBASE + 4>(x0, x1, x2, embf, a[8], a[9]);
  any_accum<LBASE + 5>(x0, x1, x2, embf, a[10], a[11]);
  any_accum<LBASE + 6>(x0, x1, x2, embf, a[12], a[13]);
  any_accum<LBASE + 7>(x0, x1, x2, embf, a[14], a[15]);

  float4* __restrict__ o = (float4*)(out + (size_t)p * 32 + LBASE * 2);
  o[0] = make_float4(a[0], a[1], a[2], a[3]);
  o[1] = make_float4(a[4], a[5], a[6], a[7]);
  o[2] = make_float4(a[8], a[9], a[10], a[11]);
  o[3] = make_float4(a[12], a[13], a[14], a[15]);
}

extern "C" void kernel_launch(void* const* d_in, const int* in_sizes, int n_in,
                              void* d_out, int out_size, void* d_ws,
                              size_t ws_size, hipStream_t stream) {
  const float* in = (const float*)d_in[0];
  const float* emb = (const float*)d_in[1];
  float* out = (float*)d_out;
  const int B = in_sizes[0] / 3;
  const size_t ws_needed = (size_t)16 * (size_t)B * sizeof(float2);

  if (ws_size >= ws_needed) {
    float2* ws = (float2*)d_ws;
    if ((B & 3) == 0) {
      const int NB = (B / 4 + 255) / 256;
      mega4_kernel<<<NB * 13, 256, 0, stream>>>(in, emb, ws, B, NB);
    } else {
      const int NB = ((B + 1) / 2 + 255) / 256;
      mega2_kernel<<<NB * 13, 256, 0, stream>>>(in, emb, ws, B, NB);
    }
    const int blocksP = (B + 255) / 256;
    final_kernel<<<blocksP, 256, 0, stream>>>(in, emb, ws, (float4*)out, B);
  } else {
    const int blocksP = (B + 255) / 256;
    grid_enc_kernel<0><<<blocksP, 256, 0, stream>>>(in, emb, out, B);
    grid_enc_kernel<8><<<blocksP, 256, 0, stream>>>(in, emb, out, B);
  }
}